// Round 1
// baseline (430.549 us; speedup 1.0000x reference)
//
#include <hip/hip_runtime.h>
#include <stdint.h>

// Problem constants (fixed by the reference)
#define BN   8192     // batch
#define DK   256      // dim
#define PN   4096     // pairs
#define CHUNK 2048    // rows of the exp matrix materialized at a time
#define NCHUNK (BN / CHUNK)

typedef __bf16  bf16_8 __attribute__((ext_vector_type(8)));
typedef __bf16  bf16_4 __attribute__((ext_vector_type(4)));
typedef float   f32x4  __attribute__((ext_vector_type(4)));

// ---------------------------------------------------------------- normalize
// One wave per row: sumsq over 256 floats, divide, write fp32 + bf16 copies.
__global__ void __launch_bounds__(256) normalize_kernel(
    const float* __restrict__ X, float* __restrict__ E, __bf16* __restrict__ Ebf) {
  const int tid  = threadIdx.x;
  const int lane = tid & 63;
  const int w    = tid >> 6;
  const int row  = blockIdx.x * 4 + w;
  float4 x = ((const float4*)(X + (size_t)row * DK))[lane];
  float ss = x.x * x.x + x.y * x.y + x.z * x.z + x.w * x.w;
  #pragma unroll
  for (int o = 32; o; o >>= 1) ss += __shfl_xor(ss, o);
  float nrm = fmaxf(sqrtf(ss), 1e-8f);
  float4 e;
  e.x = x.x / nrm; e.y = x.y / nrm; e.z = x.z / nrm; e.w = x.w / nrm;
  ((float4*)(E + (size_t)row * DK))[lane] = e;
  bf16_4 b;
  b[0] = (__bf16)e.x; b[1] = (__bf16)e.y; b[2] = (__bf16)e.z; b[3] = (__bf16)e.w;
  *(bf16_4*)(Ebf + (size_t)row * DK + lane * 4) = b;
}

// ---------------------------------------------------------------- pos values
// One wave per pair: fp32 dot over 256 dims, exp(dot/beta).
__global__ void __launch_bounds__(256) pos_kernel(
    const float* __restrict__ E, const int2* __restrict__ pairs, float* __restrict__ pos) {
  const int tid  = threadIdx.x;
  const int lane = tid & 63;
  const int w    = tid >> 6;
  const int p    = blockIdx.x * 4 + w;
  int2 pr = pairs[p];
  float4 a = ((const float4*)(E + (size_t)pr.x * DK))[lane];
  float4 b = ((const float4*)(E + (size_t)pr.y * DK))[lane];
  float d = a.x * b.x + a.y * b.y + a.z * b.z + a.w * b.w;
  #pragma unroll
  for (int o = 32; o; o >>= 1) d += __shfl_xor(d, o);
  if (lane == 0) pos[p] = __expf(5.0f * d);
}

// ------------------------------------------------ parallel bin finder (256 bins)
// hist must be complete (caller synced). Writes sh[0]=bin, sh[1]=rank within bin.
__device__ __forceinline__ void find_bin_256(const unsigned* hist, int rank,
                                             int* sh, unsigned* wtot) {
  const int tid = threadIdx.x, lane = tid & 63, w = tid >> 6;
  unsigned x = hist[tid];
  unsigned pref = x;
  #pragma unroll
  for (int o = 1; o < 64; o <<= 1) {
    unsigned y = __shfl_up(pref, o);
    if (lane >= o) pref += y;
  }
  if (lane == 63) wtot[w] = pref;
  __syncthreads();
  unsigned woff = 0;
  for (int i = 0; i < w; ++i) woff += wtot[i];
  unsigned incl = pref + woff, excl = incl - x;
  if ((unsigned)rank >= excl && (unsigned)rank < incl) { sh[0] = tid; sh[1] = rank - (int)excl; }
  __syncthreads();
}

// ---------------------------------------------------------------- pos quantile
// Single block: radix select rank 819 (ascending) over 4096 positive fp32.
__global__ void __launch_bounds__(256) pos_thr_kernel(
    const float* __restrict__ pos, float* __restrict__ thr_out) {
  __shared__ uint32_t v[PN];
  __shared__ unsigned hist[256];
  __shared__ int sh[2];
  __shared__ unsigned wtot[4];
  const int tid = threadIdx.x;
  for (int i = tid; i < PN; i += 256) v[i] = ((const uint32_t*)pos)[i];
  __syncthreads();
  int rank = 819;                 // 0.2 * 4095 = 819 (frac ~ 4.5e-13, negligible)
  uint32_t prefix = 0;
  for (int pass = 0; pass < 4; ++pass) {
    const int shift = 24 - pass * 8;
    hist[tid] = 0;
    __syncthreads();
    for (int i = tid; i < PN; i += 256) {
      uint32_t x = v[i];
      bool match = (pass == 0) || ((x >> (shift + 8)) == (prefix >> (shift + 8)));
      if (match) atomicAdd(&hist[(x >> shift) & 255u], 1u);
    }
    __syncthreads();
    find_bin_256(hist, rank, sh, wtot);
    prefix |= ((uint32_t)sh[0]) << shift;
    rank = sh[1];
    __syncthreads();
  }
  if (tid == 0) {
    float f;
    __builtin_memcpy(&f, &prefix, 4);
    thr_out[0] = f;
  }
}

// ---------------------------------------------------------------- GEMM + exp
// C = E * E^T for a 2048-row chunk; 128x128 tile, BK=32, mfma 16x16x32 bf16.
// Epilogue: out = (fp16) exp(5 * cos). Layouts per cdna_hip_programming.md §3
// (C/D: col=lane&15, row=(lane>>4)*4+reg; A/B frag: row=lane&15, k=(lane>>4)*8+j).
__global__ void __launch_bounds__(256) gemm_exp_kernel(
    const __bf16* __restrict__ E, _Float16* __restrict__ out, int row0) {
  __shared__ __align__(16) __bf16 sA[128 * 32];
  __shared__ __align__(16) __bf16 sB[128 * 32];
  const int tid  = threadIdx.x;
  const int lane = tid & 63;
  const int w    = tid >> 6;
  const int wm   = w >> 1, wn = w & 1;
  const int trow = blockIdx.y * 128;   // chunk-local row base
  const int tcol = blockIdx.x * 128;   // global col base

  f32x4 acc[4][4];
  #pragma unroll
  for (int i = 0; i < 4; ++i)
    #pragma unroll
    for (int j = 0; j < 4; ++j) {
      f32x4 z = {0.f, 0.f, 0.f, 0.f};
      acc[i][j] = z;
    }

  const int r0  = tid >> 2;        // rows 0..63
  const int r1  = 64 + (tid >> 2); // rows 64..127
  const int seg = tid & 3;         // 8-bf16 segment in the 32-wide K slice

  for (int kt = 0; kt < 8; ++kt) {
    const int k0 = kt * 32 + seg * 8;
    uint4 a0 = *(const uint4*)(E + (size_t)(row0 + trow + r0) * DK + k0);
    uint4 a1 = *(const uint4*)(E + (size_t)(row0 + trow + r1) * DK + k0);
    uint4 b0 = *(const uint4*)(E + (size_t)(tcol + r0) * DK + k0);
    uint4 b1 = *(const uint4*)(E + (size_t)(tcol + r1) * DK + k0);
    __syncthreads();
    *(uint4*)&sA[r0 * 32 + seg * 8] = a0;
    *(uint4*)&sA[r1 * 32 + seg * 8] = a1;
    *(uint4*)&sB[r0 * 32 + seg * 8] = b0;
    *(uint4*)&sB[r1 * 32 + seg * 8] = b1;
    __syncthreads();
    bf16_8 af[4], bfg[4];
    #pragma unroll
    for (int t = 0; t < 4; ++t) {
      af[t]  = *(const bf16_8*)&sA[(wm * 64 + t * 16 + (lane & 15)) * 32 + (lane >> 4) * 8];
      bfg[t] = *(const bf16_8*)&sB[(wn * 64 + t * 16 + (lane & 15)) * 32 + (lane >> 4) * 8];
    }
    #pragma unroll
    for (int i = 0; i < 4; ++i)
      #pragma unroll
      for (int j = 0; j < 4; ++j)
        acc[i][j] = __builtin_amdgcn_mfma_f32_16x16x32_bf16(af[i], bfg[j], acc[i][j], 0, 0, 0);
  }

  const int crow = trow + wm * 64 + (lane >> 4) * 4;  // chunk-local
  const int ccol = tcol + wn * 64 + (lane & 15);
  #pragma unroll
  for (int i = 0; i < 4; ++i)
    #pragma unroll
    for (int j = 0; j < 4; ++j)
      #pragma unroll
      for (int r = 0; r < 4; ++r) {
        const int row = crow + i * 16 + r;
        const int col = ccol + j * 16;
        out[(size_t)row * BN + col] = (_Float16)__expf(acc[i][j][r] * 5.0f);
      }
}

// ---------------------------------------------------------------- row stats
// One block per row: mask, radix-select s[6552]/s[6553] on fp16 bits, sum >= thr.
__global__ void __launch_bounds__(256) row_stats_kernel(
    const _Float16* __restrict__ expmat, const int2* __restrict__ pairs,
    int row0, float* __restrict__ S) {
  __shared__ __align__(16) unsigned short v[BN];
  __shared__ unsigned hist[256];
  __shared__ int sh[2];
  __shared__ unsigned wtot[4];
  __shared__ float rbuf[4];
  const int tid  = threadIdx.x;
  const int lane = tid & 63;
  const int w    = tid >> 6;
  const int rloc = blockIdx.x;
  const int row  = row0 + rloc;

  const uint4* src = (const uint4*)(expmat + (size_t)rloc * BN);
  uint4* dst = (uint4*)v;
  #pragma unroll
  for (int q = 0; q < 4; ++q) dst[tid + q * 256] = src[tid + q * 256];
  __syncthreads();
  // mask: diagonal + all pair partners of this row (exp -> 0)
  for (int p = tid; p < PN; p += 256) {
    int2 pr = pairs[p];
    if (pr.x == row) v[pr.y] = 0;
    if (pr.y == row) v[pr.x] = 0;
  }
  if (tid == 0) v[row] = 0;
  __syncthreads();

  unsigned short res[2];
  const int ranks[2] = {6552, 6553};   // floor/ceil of 0.8*8191 = 6552.8
  for (int s = 0; s < 2; ++s) {
    int rank = ranks[s];
    hist[tid] = 0;
    __syncthreads();
    for (int i = tid; i < BN; i += 256) atomicAdd(&hist[v[i] >> 8], 1u);
    __syncthreads();
    find_bin_256(hist, rank, sh, wtot);
    const int b1 = sh[0];
    rank = sh[1];
    __syncthreads();
    hist[tid] = 0;
    __syncthreads();
    for (int i = tid; i < BN; i += 256) {
      unsigned short x = v[i];
      if ((int)(x >> 8) == b1) atomicAdd(&hist[x & 255u], 1u);
    }
    __syncthreads();
    find_bin_256(hist, rank, sh, wtot);
    res[s] = (unsigned short)((b1 << 8) | sh[0]);
    __syncthreads();
  }

  float flo, fhi;
  { _Float16 h; __builtin_memcpy(&h, &res[0], 2); flo = (float)h; }
  { _Float16 h; __builtin_memcpy(&h, &res[1], 2); fhi = (float)h; }
  const float thr = flo + 0.8f * (fhi - flo);

  float local = 0.0f;
  for (int i = tid; i < BN; i += 256) {
    _Float16 h; unsigned short x = v[i];
    __builtin_memcpy(&h, &x, 2);
    float f = (float)h;
    if (f >= thr) local += f;
  }
  #pragma unroll
  for (int o = 32; o; o >>= 1) local += __shfl_xor(local, o);
  if (lane == 0) rbuf[w] = local;
  __syncthreads();
  if (tid == 0) S[row] = rbuf[0] + rbuf[1] + rbuf[2] + rbuf[3];
}

// ---------------------------------------------------------------- loss
// One block per pair-row r; active iff pos[r] <= thr (act==sel, see analysis).
__global__ void __launch_bounds__(256) loss_kernel(
    const float* __restrict__ pos, const float* __restrict__ thr_p,
    const int2* __restrict__ pairs, const float* __restrict__ S,
    float* __restrict__ acc) {
  __shared__ float rbuf[4];
  const int r = blockIdx.x;
  const float p = pos[r];
  if (p > thr_p[0]) return;
  const int tid = threadIdx.x;
  const float invp = 1.0f / p;
  float local = 0.0f;
  for (int c = tid; c < PN; c += 256) {
    int2 pr = pairs[c];
    local += log1pf(S[pr.x] * invp) + log1pf(S[pr.y] * invp);
  }
  #pragma unroll
  for (int o = 32; o; o >>= 1) local += __shfl_xor(local, o);
  const int lane = tid & 63, w = tid >> 6;
  if (lane == 0) rbuf[w] = local;
  __syncthreads();
  if (tid == 0) atomicAdd(acc, rbuf[0] + rbuf[1] + rbuf[2] + rbuf[3]);
}

__global__ void finalize_kernel(const float* __restrict__ acc, float* __restrict__ out) {
  out[0] = acc[0] * (1.0f / (2.0f * (float)PN));
}

// ---------------------------------------------------------------- launch
extern "C" void kernel_launch(void* const* d_in, const int* in_sizes, int n_in,
                              void* d_out, int out_size, void* d_ws, size_t ws_size,
                              hipStream_t stream) {
  const float* emb  = (const float*)d_in[0];
  const int2* pairs = (const int2*)d_in[1];
  float* out = (float*)d_out;

  // workspace layout (~46 MB total)
  char* w = (char*)d_ws;
  size_t off = 0;
  float*    E    = (float*)(w + off);    off += (size_t)BN * DK * 4;     // 8 MB
  __bf16*   Ebf  = (__bf16*)(w + off);   off += (size_t)BN * DK * 2;     // 4 MB
  float*    S    = (float*)(w + off);    off += (size_t)BN * 4;
  float*    pos  = (float*)(w + off);    off += (size_t)PN * 4;
  float*    thrp = (float*)(w + off);    off += 256;
  float*    acc  = (float*)(w + off);    off += 256;
  _Float16* expc = (_Float16*)(w + off); off += (size_t)CHUNK * BN * 2;  // 33.5 MB

  hipMemsetAsync(acc, 0, sizeof(float), stream);
  normalize_kernel<<<BN / 4, 256, 0, stream>>>(emb, E, Ebf);
  pos_kernel<<<PN / 4, 256, 0, stream>>>(E, pairs, pos);
  pos_thr_kernel<<<1, 256, 0, stream>>>(pos, thrp);
  for (int c = 0; c < NCHUNK; ++c) {
    const int row0 = c * CHUNK;
    gemm_exp_kernel<<<dim3(BN / 128, CHUNK / 128), 256, 0, stream>>>(Ebf, expc, row0);
    row_stats_kernel<<<CHUNK, 256, 0, stream>>>(expc, pairs, row0, S);
  }
  loss_kernel<<<PN, 256, 0, stream>>>(pos, thrp, pairs, S, acc);
  finalize_kernel<<<1, 1, 0, stream>>>(acc, out);
}

// Round 2
// 237.618 us; speedup vs baseline: 1.8119x; 1.8119x over previous
//
#include <hip/hip_runtime.h>
#include <stdint.h>

// Problem constants (fixed by the reference)
#define BN    8192    // batch
#define DK    256     // dim
#define PN    4096    // pairs
#define CHUNK 2048    // compacted rows of the exp matrix materialized at a time
#define NCHUNK 4
#define MAXP  16      // max partners tracked per row (Poisson(1); P(>16) ~ 1e-15)
#define HBASE 0x340   // fp16 (bits>>4) base: bins cover values [0.25, ~3.97]
#define RANK_ASC 6553 // ascending rank for the 0.8 quantile boundary (top-1639)

typedef __bf16  bf16_8 __attribute__((ext_vector_type(8)));
typedef __bf16  bf16_4 __attribute__((ext_vector_type(4)));
typedef float   f32x4  __attribute__((ext_vector_type(4)));

__device__ __forceinline__ void gload_lds16(const void* g, void* l) {
  __builtin_amdgcn_global_load_lds(
      (const __attribute__((address_space(1))) unsigned int*)g,
      (__attribute__((address_space(3))) unsigned int*)l, 16, 0, 0);
}

// ---------------------------------------------------------------- prep
__global__ void prep_clear_kernel(int* pcount, int* rowlist, int* cnt, float* acc) {
  const int i = blockIdx.x * 256 + threadIdx.x;
  if (i < BN) { pcount[i] = 0; rowlist[i] = 0; }
  if (i == 0) { cnt[0] = 0; acc[0] = 0.f; }
}

__global__ void prep_pairs_kernel(const int2* __restrict__ pairs,
                                  int* pcount, int* partners) {
  const int p = blockIdx.x * 256 + threadIdx.x;
  if (p >= PN) return;
  int2 pr = pairs[p];
  int ix = atomicAdd(&pcount[pr.x], 1);
  if (ix < MAXP) partners[pr.x * MAXP + ix] = pr.y;
  int iy = atomicAdd(&pcount[pr.y], 1);
  if (iy < MAXP) partners[pr.y * MAXP + iy] = pr.x;
}

__global__ void prep_compact_kernel(const int* __restrict__ pcount,
                                    int* rowlist, int* cnt) {
  const int i = blockIdx.x * 256 + threadIdx.x;
  if (i < BN && pcount[i] > 0) {
    int pos = atomicAdd(cnt, 1);
    rowlist[pos] = i;
  }
}

// ---------------------------------------------------------------- normalize
__global__ void __launch_bounds__(256) normalize_kernel(
    const float* __restrict__ X, float* __restrict__ E, __bf16* __restrict__ Ebf) {
  const int tid  = threadIdx.x;
  const int lane = tid & 63;
  const int w    = tid >> 6;
  const int row  = blockIdx.x * 4 + w;
  float4 x = ((const float4*)(X + (size_t)row * DK))[lane];
  float ss = x.x * x.x + x.y * x.y + x.z * x.z + x.w * x.w;
  #pragma unroll
  for (int o = 32; o; o >>= 1) ss += __shfl_xor(ss, o);
  float nrm = fmaxf(sqrtf(ss), 1e-8f);
  float4 e;
  e.x = x.x / nrm; e.y = x.y / nrm; e.z = x.z / nrm; e.w = x.w / nrm;
  ((float4*)(E + (size_t)row * DK))[lane] = e;
  bf16_4 b;
  b[0] = (__bf16)e.x; b[1] = (__bf16)e.y; b[2] = (__bf16)e.z; b[3] = (__bf16)e.w;
  *(bf16_4*)(Ebf + (size_t)row * DK + lane * 4) = b;
}

// ---------------------------------------------------------------- pos values
__global__ void __launch_bounds__(256) pos_kernel(
    const float* __restrict__ E, const int2* __restrict__ pairs, float* __restrict__ pos) {
  const int tid  = threadIdx.x;
  const int lane = tid & 63;
  const int w    = tid >> 6;
  const int p    = blockIdx.x * 4 + w;
  int2 pr = pairs[p];
  float4 a = ((const float4*)(E + (size_t)pr.x * DK))[lane];
  float4 b = ((const float4*)(E + (size_t)pr.y * DK))[lane];
  float d = a.x * b.x + a.y * b.y + a.z * b.z + a.w * b.w;
  #pragma unroll
  for (int o = 32; o; o >>= 1) d += __shfl_xor(d, o);
  if (lane == 0) pos[p] = __expf(5.0f * d);
}

// ------------------------------------------------ parallel bin finder (256 bins)
__device__ __forceinline__ void find_bin_256(const unsigned* hist, int rank,
                                             int* sh, unsigned* wtot) {
  const int tid = threadIdx.x, lane = tid & 63, w = tid >> 6;
  unsigned x = hist[tid];
  unsigned pref = x;
  #pragma unroll
  for (int o = 1; o < 64; o <<= 1) {
    unsigned y = __shfl_up(pref, o);
    if (lane >= o) pref += y;
  }
  if (lane == 63) wtot[w] = pref;
  __syncthreads();
  unsigned woff = 0;
  for (int i = 0; i < w; ++i) woff += wtot[i];
  unsigned incl = pref + woff, excl = incl - x;
  if ((unsigned)rank >= excl && (unsigned)rank < incl) { sh[0] = tid; sh[1] = rank - (int)excl; }
  __syncthreads();
}

// ---------------------------------------------------------------- pos quantile
// Single block: exact radix select rank 819 over 4096 positive fp32.
__global__ void __launch_bounds__(256) pos_thr_kernel(
    const float* __restrict__ pos, float* __restrict__ thr_out) {
  __shared__ uint32_t v[PN];
  __shared__ unsigned hist[256];
  __shared__ int sh[2];
  __shared__ unsigned wtot[4];
  const int tid = threadIdx.x;
  for (int i = tid; i < PN; i += 256) v[i] = ((const uint32_t*)pos)[i];
  __syncthreads();
  int rank = 819;                 // 0.2 * 4095 = 819 exactly
  uint32_t prefix = 0;
  for (int pass = 0; pass < 4; ++pass) {
    const int shift = 24 - pass * 8;
    hist[tid] = 0;
    __syncthreads();
    for (int i = tid; i < PN; i += 256) {
      uint32_t x = v[i];
      bool match = (pass == 0) || ((x >> (shift + 8)) == (prefix >> (shift + 8)));
      if (match) atomicAdd(&hist[(x >> shift) & 255u], 1u);
    }
    __syncthreads();
    find_bin_256(hist, rank, sh, wtot);
    prefix |= ((uint32_t)sh[0]) << shift;
    rank = sh[1];
    __syncthreads();
  }
  if (tid == 0) {
    float f;
    __builtin_memcpy(&f, &prefix, 4);
    thr_out[0] = f;
  }
}

// ---------------------------------------------------------------- GEMM + exp
// C[compact_row, col] = exp(5 * E[rowlist[row]] . E[col]); 128x128 tile, BK=32,
// mfma 16x16x32 bf16, global_load_lds(16B) staging.
__global__ void __launch_bounds__(256) gemm_exp_kernel(
    const __bf16* __restrict__ E, const int* __restrict__ rowlist,
    const int* __restrict__ countp, _Float16* __restrict__ out, int row0) {
  if (row0 + (int)blockIdx.y * 128 >= *countp) return;
  __shared__ __align__(16) __bf16 sA[128 * 32];
  __shared__ __align__(16) __bf16 sB[128 * 32];
  const int tid  = threadIdx.x;
  const int lane = tid & 63;
  const int w    = tid >> 6;
  const int wm   = w >> 1, wn = w & 1;
  const int trow = blockIdx.y * 128;   // compact-row base (chunk-local + row0)
  const int tcol = blockIdx.x * 128;   // global col base
  const int r0   = tid >> 2;           // rows 0..63
  const int seg  = tid & 3;            // 8-bf16 segment of the 32-wide K slice

  const int ga0 = rowlist[row0 + trow + r0];
  const int ga1 = rowlist[row0 + trow + 64 + r0];
  const __bf16* pa0 = E + (size_t)ga0 * DK + seg * 8;
  const __bf16* pa1 = E + (size_t)ga1 * DK + seg * 8;
  const __bf16* pb0 = E + (size_t)(tcol + r0) * DK + seg * 8;
  const __bf16* pb1 = E + (size_t)(tcol + 64 + r0) * DK + seg * 8;
  __bf16* la0 = &sA[tid * 8];          // r0*32 + seg*8 == tid*8 (lane*16B + wave base)
  __bf16* la1 = &sA[2048 + tid * 8];
  __bf16* lb0 = &sB[tid * 8];
  __bf16* lb1 = &sB[2048 + tid * 8];

  f32x4 acc[4][4];
  #pragma unroll
  for (int i = 0; i < 4; ++i)
    #pragma unroll
    for (int j = 0; j < 4; ++j) {
      f32x4 z = {0.f, 0.f, 0.f, 0.f};
      acc[i][j] = z;
    }

  for (int kt = 0; kt < 8; ++kt) {
    const int k0 = kt * 32;
    __syncthreads();
    gload_lds16(pa0 + k0, la0);
    gload_lds16(pa1 + k0, la1);
    gload_lds16(pb0 + k0, lb0);
    gload_lds16(pb1 + k0, lb1);
    __syncthreads();
    bf16_8 af[4], bfg[4];
    #pragma unroll
    for (int t = 0; t < 4; ++t) {
      af[t]  = *(const bf16_8*)&sA[(wm * 64 + t * 16 + (lane & 15)) * 32 + (lane >> 4) * 8];
      bfg[t] = *(const bf16_8*)&sB[(wn * 64 + t * 16 + (lane & 15)) * 32 + (lane >> 4) * 8];
    }
    #pragma unroll
    for (int i = 0; i < 4; ++i)
      #pragma unroll
      for (int j = 0; j < 4; ++j)
        acc[i][j] = __builtin_amdgcn_mfma_f32_16x16x32_bf16(af[i], bfg[j], acc[i][j], 0, 0, 0);
  }

  const int crow = trow + wm * 64 + (lane >> 4) * 4;  // chunk-local compact row
  const int ccol = tcol + wn * 64 + (lane & 15);
  #pragma unroll
  for (int i = 0; i < 4; ++i)
    #pragma unroll
    for (int j = 0; j < 4; ++j)
      #pragma unroll
      for (int r = 0; r < 4; ++r) {
        const int row = crow + i * 16 + r;
        const int col = ccol + j * 16;
        out[(size_t)row * BN + col] = (_Float16)__expf(acc[i][j][r] * 5.0f);
      }
}

// ---------------------------------------------------------------- row stats v2
// One block per compacted row. Row values live in REGISTERS (32 fp16/thread,
// col = q*2048 + tid*8 + j). One privatized-histogram pass on spread bins
// ((bits>>4)-HBASE), select ascending rank 6553, then S = sum(bin>b) +
// need * mean(bin b). Approximation error ~0.03% of S (bin width ~1.5% rel).
__global__ void __launch_bounds__(256) row_stats_kernel(
    const _Float16* __restrict__ expmat, const int* __restrict__ rowlist,
    const int* __restrict__ countp, const int* __restrict__ pcount,
    const int* __restrict__ partners, int row0, float* __restrict__ S) {
  __shared__ unsigned hist[4][256];
  __shared__ unsigned total[256];
  __shared__ int plist[MAXP + 1];
  __shared__ int sh[2];
  __shared__ unsigned wtot[4];
  __shared__ float redf[2][4];
  __shared__ unsigned redc[4];
  const int rloc = blockIdx.x;
  if (row0 + rloc >= *countp) return;     // uniform early exit (unused rows)
  const int grow = rowlist[row0 + rloc];
  const int tid = threadIdx.x, lane = tid & 63, w = tid >> 6;

  // coalesced load: thread tid holds columns {q*2048 + tid*8 + j}
  uint4 rv[4];
  const uint4* src = (const uint4*)(expmat + (size_t)rloc * BN);
  #pragma unroll
  for (int q = 0; q < 4; ++q) rv[q] = src[q * 256 + tid];

  int np = pcount[grow]; if (np > MAXP) np = MAXP;
  if (tid < np) plist[tid] = partners[grow * MAXP + tid];
  if (tid == np) plist[tid] = grow;       // diagonal
  ((unsigned*)hist)[tid]       = 0;
  ((unsigned*)hist)[tid + 256] = 0;
  ((unsigned*)hist)[tid + 512] = 0;
  ((unsigned*)hist)[tid + 768] = 0;
  __syncthreads();

  unsigned short hv[32];
  #pragma unroll
  for (int q = 0; q < 4; ++q) {
    union { uint4 u; unsigned short s[8]; } cv;
    cv.u = rv[q];
    #pragma unroll
    for (int j = 0; j < 8; ++j) hv[q * 8 + j] = cv.s[j];
  }

  // mask: zero partner columns + diagonal owned by this thread
  for (int e = 0; e <= np; ++e) {
    int c = plist[e];
    if (((c >> 3) & 255) == tid) hv[((c >> 11) << 3) | (c & 7)] = 0;
  }

  // single histogram pass, per-wave privatized
  unsigned* h = hist[w];
  #pragma unroll
  for (int e = 0; e < 32; ++e) {
    int bb = (int)(hv[e] >> 4) - HBASE;
    bb = bb < 0 ? 0 : (bb > 255 ? 255 : bb);
    atomicAdd(&h[bb], 1u);
  }
  __syncthreads();
  total[tid] = hist[0][tid] + hist[1][tid] + hist[2][tid] + hist[3][tid];
  __syncthreads();
  find_bin_256(total, RANK_ASC, sh, wtot);
  const int b    = sh[0];
  const int need = (int)total[b] - sh[1];  // how many of bin b are in the top-1639

  // register pass: sum above-bin + in-bin stats
  float shi = 0.f, sin_ = 0.f; unsigned cin = 0;
  #pragma unroll
  for (int e = 0; e < 32; ++e) {
    unsigned short x = hv[e];
    int bb = (int)(x >> 4) - HBASE;
    bb = bb < 0 ? 0 : (bb > 255 ? 255 : bb);
    _Float16 hf; __builtin_memcpy(&hf, &x, 2);
    float v = (float)hf;
    if (bb > b) shi += v;
    else if (bb == b) { sin_ += v; cin++; }
  }
  #pragma unroll
  for (int o = 32; o; o >>= 1) {
    shi  += __shfl_xor(shi, o);
    sin_ += __shfl_xor(sin_, o);
    cin  += __shfl_xor(cin, o);
  }
  if (lane == 0) { redf[0][w] = shi; redf[1][w] = sin_; redc[w] = cin; }
  __syncthreads();
  if (tid == 0) {
    float SHI = redf[0][0] + redf[0][1] + redf[0][2] + redf[0][3];
    float SIN = redf[1][0] + redf[1][1] + redf[1][2] + redf[1][3];
    float CIN = (float)(redc[0] + redc[1] + redc[2] + redc[3]);
    S[grow] = SHI + (float)need * (SIN / CIN);
  }
}

// ---------------------------------------------------------------- loss
__global__ void __launch_bounds__(256) loss_kernel(
    const float* __restrict__ pos, const float* __restrict__ thr_p,
    const int2* __restrict__ pairs, const float* __restrict__ S,
    float* __restrict__ acc) {
  __shared__ float rbuf[4];
  const int r = blockIdx.x;
  const float p = pos[r];
  if (p > thr_p[0]) return;
  const int tid = threadIdx.x;
  const float invp = 1.0f / p;
  float local = 0.0f;
  for (int c = tid; c < PN; c += 256) {
    int2 pr = pairs[c];
    local += log1pf(S[pr.x] * invp) + log1pf(S[pr.y] * invp);
  }
  #pragma unroll
  for (int o = 32; o; o >>= 1) local += __shfl_xor(local, o);
  const int lane = tid & 63, w = tid >> 6;
  if (lane == 0) rbuf[w] = local;
  __syncthreads();
  if (tid == 0) atomicAdd(acc, rbuf[0] + rbuf[1] + rbuf[2] + rbuf[3]);
}

__global__ void finalize_kernel(const float* __restrict__ acc, float* __restrict__ out) {
  out[0] = acc[0] * (1.0f / (2.0f * (float)PN));
}

// ---------------------------------------------------------------- launch
extern "C" void kernel_launch(void* const* d_in, const int* in_sizes, int n_in,
                              void* d_out, int out_size, void* d_ws, size_t ws_size,
                              hipStream_t stream) {
  const float* emb  = (const float*)d_in[0];
  const int2* pairs = (const int2*)d_in[1];
  float* out = (float*)d_out;

  char* w = (char*)d_ws;
  size_t off = 0;
  float*    E     = (float*)(w + off);    off += (size_t)BN * DK * 4;      // 8 MB
  __bf16*   Ebf   = (__bf16*)(w + off);   off += (size_t)BN * DK * 2;      // 4 MB
  float*    S     = (float*)(w + off);    off += (size_t)BN * 4;
  float*    pos   = (float*)(w + off);    off += (size_t)PN * 4;
  float*    thrp  = (float*)(w + off);    off += 256;
  float*    acc   = (float*)(w + off);    off += 256;
  int*      pcnt  = (int*)(w + off);      off += (size_t)BN * 4;
  int*      parts = (int*)(w + off);      off += (size_t)BN * MAXP * 4;    // 512 KB
  int*      rlist = (int*)(w + off);      off += (size_t)BN * 4;
  int*      cnt   = (int*)(w + off);      off += 256;
  _Float16* expc  = (_Float16*)(w + off); off += (size_t)CHUNK * BN * 2;   // 33.5 MB

  prep_clear_kernel<<<BN / 256, 256, 0, stream>>>(pcnt, rlist, cnt, acc);
  normalize_kernel<<<BN / 4, 256, 0, stream>>>(emb, E, Ebf);
  prep_pairs_kernel<<<PN / 256, 256, 0, stream>>>(pairs, pcnt, parts);
  prep_compact_kernel<<<BN / 256, 256, 0, stream>>>(pcnt, rlist, cnt);
  pos_kernel<<<PN / 4, 256, 0, stream>>>(E, pairs, pos);
  pos_thr_kernel<<<1, 256, 0, stream>>>(pos, thrp);
  for (int c = 0; c < NCHUNK; ++c) {
    const int row0 = c * CHUNK;
    gemm_exp_kernel<<<dim3(BN / 128, CHUNK / 128), 256, 0, stream>>>(Ebf, rlist, cnt, expc, row0);
    row_stats_kernel<<<CHUNK, 256, 0, stream>>>(expc, rlist, cnt, pcnt, parts, row0, S);
  }
  loss_kernel<<<PN, 256, 0, stream>>>(pos, thrp, pairs, S, acc);
  finalize_kernel<<<1, 1, 0, stream>>>(acc, out);
}

// Round 3
// 209.440 us; speedup vs baseline: 2.0557x; 1.1345x over previous
//
#include <hip/hip_runtime.h>
#include <stdint.h>

// Problem constants (fixed by the reference)
#define BN    8192    // batch
#define DK    256     // dim
#define PN    4096    // pairs
#define CHUNK 2048    // compacted rows of the exp matrix materialized at a time
#define NCHUNK 4
#define MAXP  16      // max partners tracked per row (Poisson(1); P(>16) ~ 1e-15)
#define HBASE 0x340   // fp16 (bits>>4) base: bins cover values [0.25, ~3.97]
#define RANK_ASC 6553 // ascending rank for the 0.8 quantile boundary (top-1639)

typedef __bf16  bf16_8 __attribute__((ext_vector_type(8)));
typedef __bf16  bf16_4 __attribute__((ext_vector_type(4)));
typedef float   f32x4  __attribute__((ext_vector_type(4)));

__device__ __forceinline__ void gload_lds16(const void* g, void* l) {
  __builtin_amdgcn_global_load_lds(
      (const __attribute__((address_space(1))) unsigned int*)g,
      (__attribute__((address_space(3))) unsigned int*)l, 16, 0, 0);
}

// ---------------------------------------------------------------- prep
__global__ void prep_clear_kernel(int* pcount, int* rowlist, int* cnt, float* acc) {
  const int i = blockIdx.x * 256 + threadIdx.x;
  if (i < BN) { pcount[i] = 0; rowlist[i] = 0; }
  if (i < 8) acc[i] = 0.f;
  if (i == 0) cnt[0] = 0;
}

__global__ void prep_pairs_kernel(const int2* __restrict__ pairs,
                                  int* pcount, int* partners) {
  const int p = blockIdx.x * 256 + threadIdx.x;
  if (p >= PN) return;
  int2 pr = pairs[p];
  int ix = atomicAdd(&pcount[pr.x], 1);
  if (ix < MAXP) partners[pr.x * MAXP + ix] = pr.y;
  int iy = atomicAdd(&pcount[pr.y], 1);
  if (iy < MAXP) partners[pr.y * MAXP + iy] = pr.x;
}

__global__ void prep_compact_kernel(const int* __restrict__ pcount,
                                    int* rowlist, int* cnt) {
  const int i = blockIdx.x * 256 + threadIdx.x;
  if (i < BN && pcount[i] > 0) {
    int pos = atomicAdd(cnt, 1);
    rowlist[pos] = i;
  }
}

// ---------------------------------------------------------------- normalize
__global__ void __launch_bounds__(256) normalize_kernel(
    const float* __restrict__ X, float* __restrict__ E, __bf16* __restrict__ Ebf) {
  const int tid  = threadIdx.x;
  const int lane = tid & 63;
  const int w    = tid >> 6;
  const int row  = blockIdx.x * 4 + w;
  float4 x = ((const float4*)(X + (size_t)row * DK))[lane];
  float ss = x.x * x.x + x.y * x.y + x.z * x.z + x.w * x.w;
  #pragma unroll
  for (int o = 32; o; o >>= 1) ss += __shfl_xor(ss, o);
  float nrm = fmaxf(sqrtf(ss), 1e-8f);
  float4 e;
  e.x = x.x / nrm; e.y = x.y / nrm; e.z = x.z / nrm; e.w = x.w / nrm;
  ((float4*)(E + (size_t)row * DK))[lane] = e;
  bf16_4 b;
  b[0] = (__bf16)e.x; b[1] = (__bf16)e.y; b[2] = (__bf16)e.z; b[3] = (__bf16)e.w;
  *(bf16_4*)(Ebf + (size_t)row * DK + lane * 4) = b;
}

// ---------------------------------------------------------------- pos values
__global__ void __launch_bounds__(256) pos_kernel(
    const float* __restrict__ E, const int2* __restrict__ pairs, float* __restrict__ pos) {
  const int tid  = threadIdx.x;
  const int lane = tid & 63;
  const int w    = tid >> 6;
  const int p    = blockIdx.x * 4 + w;
  int2 pr = pairs[p];
  float4 a = ((const float4*)(E + (size_t)pr.x * DK))[lane];
  float4 b = ((const float4*)(E + (size_t)pr.y * DK))[lane];
  float d = a.x * b.x + a.y * b.y + a.z * b.z + a.w * b.w;
  #pragma unroll
  for (int o = 32; o; o >>= 1) d += __shfl_xor(d, o);
  if (lane == 0) pos[p] = __expf(5.0f * d);
}

// ------------------------------------------------ parallel bin finder (256 bins)
__device__ __forceinline__ void find_bin_256(const unsigned* hist, int rank,
                                             int* sh, unsigned* wtot) {
  const int tid = threadIdx.x, lane = tid & 63, w = tid >> 6;
  unsigned x = hist[tid];
  unsigned pref = x;
  #pragma unroll
  for (int o = 1; o < 64; o <<= 1) {
    unsigned y = __shfl_up(pref, o);
    if (lane >= o) pref += y;
  }
  if (lane == 63) wtot[w] = pref;
  __syncthreads();
  unsigned woff = 0;
  for (int i = 0; i < w; ++i) woff += wtot[i];
  unsigned incl = pref + woff, excl = incl - x;
  if ((unsigned)rank >= excl && (unsigned)rank < incl) { sh[0] = tid; sh[1] = rank - (int)excl; }
  __syncthreads();
}

// ---------------------------------------------------------------- pos quantile
// Single block: exact radix select rank 819 over 4096 positive fp32.
__global__ void __launch_bounds__(256) pos_thr_kernel(
    const float* __restrict__ pos, float* __restrict__ thr_out) {
  __shared__ uint32_t v[PN];
  __shared__ unsigned hist[256];
  __shared__ int sh[2];
  __shared__ unsigned wtot[4];
  const int tid = threadIdx.x;
  for (int i = tid; i < PN; i += 256) v[i] = ((const uint32_t*)pos)[i];
  __syncthreads();
  int rank = 819;                 // 0.2 * 4095 = 819 exactly
  uint32_t prefix = 0;
  for (int pass = 0; pass < 4; ++pass) {
    const int shift = 24 - pass * 8;
    hist[tid] = 0;
    __syncthreads();
    for (int i = tid; i < PN; i += 256) {
      uint32_t x = v[i];
      bool match = (pass == 0) || ((x >> (shift + 8)) == (prefix >> (shift + 8)));
      if (match) atomicAdd(&hist[(x >> shift) & 255u], 1u);
    }
    __syncthreads();
    find_bin_256(hist, rank, sh, wtot);
    prefix |= ((uint32_t)sh[0]) << shift;
    rank = sh[1];
    __syncthreads();
  }
  if (tid == 0) {
    float f;
    __builtin_memcpy(&f, &prefix, 4);
    thr_out[0] = f;
  }
}

// ---------------------------------------------------------------- GEMM + exp
// C[compact_row, col] = exp(5 * E[rowlist[row]] . E[col]); 128x128 tile, BK=32,
// mfma 16x16x32 bf16, global_load_lds(16B) staging.
__global__ void __launch_bounds__(256) gemm_exp_kernel(
    const __bf16* __restrict__ E, const int* __restrict__ rowlist,
    const int* __restrict__ countp, _Float16* __restrict__ out, int row0) {
  if (row0 + (int)blockIdx.y * 128 >= *countp) return;
  __shared__ __align__(16) __bf16 sA[128 * 32];
  __shared__ __align__(16) __bf16 sB[128 * 32];
  const int tid  = threadIdx.x;
  const int lane = tid & 63;
  const int w    = tid >> 6;
  const int wm   = w >> 1, wn = w & 1;
  const int trow = blockIdx.y * 128;   // compact-row base (chunk-local + row0)
  const int tcol = blockIdx.x * 128;   // global col base
  const int r0   = tid >> 2;           // rows 0..63
  const int seg  = tid & 3;            // 8-bf16 segment of the 32-wide K slice

  const int ga0 = rowlist[row0 + trow + r0];
  const int ga1 = rowlist[row0 + trow + 64 + r0];
  const __bf16* pa0 = E + (size_t)ga0 * DK + seg * 8;
  const __bf16* pa1 = E + (size_t)ga1 * DK + seg * 8;
  const __bf16* pb0 = E + (size_t)(tcol + r0) * DK + seg * 8;
  const __bf16* pb1 = E + (size_t)(tcol + 64 + r0) * DK + seg * 8;
  __bf16* la0 = &sA[tid * 8];          // r0*32 + seg*8 == tid*8
  __bf16* la1 = &sA[2048 + tid * 8];
  __bf16* lb0 = &sB[tid * 8];
  __bf16* lb1 = &sB[2048 + tid * 8];

  f32x4 acc[4][4];
  #pragma unroll
  for (int i = 0; i < 4; ++i)
    #pragma unroll
    for (int j = 0; j < 4; ++j) {
      f32x4 z = {0.f, 0.f, 0.f, 0.f};
      acc[i][j] = z;
    }

  for (int kt = 0; kt < 8; ++kt) {
    const int k0 = kt * 32;
    __syncthreads();
    gload_lds16(pa0 + k0, la0);
    gload_lds16(pa1 + k0, la1);
    gload_lds16(pb0 + k0, lb0);
    gload_lds16(pb1 + k0, lb1);
    __syncthreads();
    bf16_8 af[4], bfg[4];
    #pragma unroll
    for (int t = 0; t < 4; ++t) {
      af[t]  = *(const bf16_8*)&sA[(wm * 64 + t * 16 + (lane & 15)) * 32 + (lane >> 4) * 8];
      bfg[t] = *(const bf16_8*)&sB[(wn * 64 + t * 16 + (lane & 15)) * 32 + (lane >> 4) * 8];
    }
    #pragma unroll
    for (int i = 0; i < 4; ++i)
      #pragma unroll
      for (int j = 0; j < 4; ++j)
        acc[i][j] = __builtin_amdgcn_mfma_f32_16x16x32_bf16(af[i], bfg[j], acc[i][j], 0, 0, 0);
  }

  const int crow = trow + wm * 64 + (lane >> 4) * 4;  // chunk-local compact row
  const int ccol = tcol + wn * 64 + (lane & 15);
  #pragma unroll
  for (int i = 0; i < 4; ++i)
    #pragma unroll
    for (int j = 0; j < 4; ++j)
      #pragma unroll
      for (int r = 0; r < 4; ++r) {
        const int row = crow + i * 16 + r;
        const int col = ccol + j * 16;
        out[(size_t)row * BN + col] = (_Float16)__expf(acc[i][j][r] * 5.0f);
      }
}

// ---------------------------------------------------------------- row stats v2
// One block per compacted row; values in registers; one privatized histogram
// pass on spread fp16 bins; S = sum(bin>b) + need * mean(bin b).
__global__ void __launch_bounds__(256) row_stats_kernel(
    const _Float16* __restrict__ expmat, const int* __restrict__ rowlist,
    const int* __restrict__ countp, const int* __restrict__ pcount,
    const int* __restrict__ partners, int row0, float* __restrict__ S) {
  __shared__ unsigned hist[4][256];
  __shared__ unsigned total[256];
  __shared__ int plist[MAXP + 1];
  __shared__ int sh[2];
  __shared__ unsigned wtot[4];
  __shared__ float redf[2][4];
  __shared__ unsigned redc[4];
  const int rloc = blockIdx.x;
  if (row0 + rloc >= *countp) return;     // uniform early exit (unused rows)
  const int grow = rowlist[row0 + rloc];
  const int tid = threadIdx.x, lane = tid & 63, w = tid >> 6;

  uint4 rv[4];
  const uint4* src = (const uint4*)(expmat + (size_t)rloc * BN);
  #pragma unroll
  for (int q = 0; q < 4; ++q) rv[q] = src[q * 256 + tid];

  int np = pcount[grow]; if (np > MAXP) np = MAXP;
  if (tid < np) plist[tid] = partners[grow * MAXP + tid];
  if (tid == np) plist[tid] = grow;       // diagonal
  ((unsigned*)hist)[tid]       = 0;
  ((unsigned*)hist)[tid + 256] = 0;
  ((unsigned*)hist)[tid + 512] = 0;
  ((unsigned*)hist)[tid + 768] = 0;
  __syncthreads();

  unsigned short hv[32];
  #pragma unroll
  for (int q = 0; q < 4; ++q) {
    union { uint4 u; unsigned short s[8]; } cv;
    cv.u = rv[q];
    #pragma unroll
    for (int j = 0; j < 8; ++j) hv[q * 8 + j] = cv.s[j];
  }

  for (int e = 0; e <= np; ++e) {
    int c = plist[e];
    if (((c >> 3) & 255) == tid) hv[((c >> 11) << 3) | (c & 7)] = 0;
  }

  unsigned* h = hist[w];
  #pragma unroll
  for (int e = 0; e < 32; ++e) {
    int bb = (int)(hv[e] >> 4) - HBASE;
    bb = bb < 0 ? 0 : (bb > 255 ? 255 : bb);
    atomicAdd(&h[bb], 1u);
  }
  __syncthreads();
  total[tid] = hist[0][tid] + hist[1][tid] + hist[2][tid] + hist[3][tid];
  __syncthreads();
  find_bin_256(total, RANK_ASC, sh, wtot);
  const int b    = sh[0];
  const int need = (int)total[b] - sh[1];

  float shi = 0.f, sin_ = 0.f; unsigned cin = 0;
  #pragma unroll
  for (int e = 0; e < 32; ++e) {
    unsigned short x = hv[e];
    int bb = (int)(x >> 4) - HBASE;
    bb = bb < 0 ? 0 : (bb > 255 ? 255 : bb);
    _Float16 hf; __builtin_memcpy(&hf, &x, 2);
    float v = (float)hf;
    if (bb > b) shi += v;
    else if (bb == b) { sin_ += v; cin++; }
  }
  #pragma unroll
  for (int o = 32; o; o >>= 1) {
    shi  += __shfl_xor(shi, o);
    sin_ += __shfl_xor(sin_, o);
    cin  += __shfl_xor(cin, o);
  }
  if (lane == 0) { redf[0][w] = shi; redf[1][w] = sin_; redc[w] = cin; }
  __syncthreads();
  if (tid == 0) {
    float SHI = redf[0][0] + redf[0][1] + redf[0][2] + redf[0][3];
    float SIN = redf[1][0] + redf[1][1] + redf[1][2] + redf[1][3];
    float CIN = (float)(redc[0] + redc[1] + redc[2] + redc[3]);
    S[grow] = SHI + (float)need * (SIN / CIN);
  }
}

// ---------------------------------------------------------------- loss (factorized)
// log1p(S/p) = logS - logp + p/S - p^2/(2S^2) + O((p/S)^3), p/S <= ~3e-4.
// Double sum factorizes: n*T - 2P*sl + sp*U - 0.5*sp2*V, with
// T=sum_c logS_c, U=sum_c 1/S_c, V=sum_c 1/S_c^2 over the 8192 pair-slots,
// and n, sl=sum logp, sp=sum p, sp2=sum p^2 over active rows.
// acc layout: [0]=T [1]=U [2]=V [3]=n [4]=sl [5]=sp [6]=sp2
__global__ void __launch_bounds__(256) pair_terms_kernel(
    const int2* __restrict__ pairs, const float* __restrict__ S,
    float* __restrict__ acc) {
  __shared__ float red[3][4];
  const int tid = threadIdx.x, lane = tid & 63, w = tid >> 6;
  float t = 0.f, u = 0.f, v = 0.f;
  for (int c = tid; c < PN; c += 256) {
    int2 pr = pairs[c];
    float s1 = S[pr.x], s2 = S[pr.y];
    float i1 = 1.f / s1, i2 = 1.f / s2;
    t += __logf(s1) + __logf(s2);
    u += i1 + i2;
    v += i1 * i1 + i2 * i2;
  }
  #pragma unroll
  for (int o = 32; o; o >>= 1) {
    t += __shfl_xor(t, o); u += __shfl_xor(u, o); v += __shfl_xor(v, o);
  }
  if (lane == 0) { red[0][w] = t; red[1][w] = u; red[2][w] = v; }
  __syncthreads();
  if (tid == 0) {
    acc[0] = red[0][0] + red[0][1] + red[0][2] + red[0][3];
    acc[1] = red[1][0] + red[1][1] + red[1][2] + red[1][3];
    acc[2] = red[2][0] + red[2][1] + red[2][2] + red[2][3];
  }
}

__global__ void __launch_bounds__(256) active_sums_kernel(
    const float* __restrict__ pos, const float* __restrict__ thr_p,
    float* __restrict__ acc) {
  __shared__ float red[4][4];
  const int tid = threadIdx.x, lane = tid & 63, w = tid >> 6;
  const float thr = thr_p[0];
  float n = 0.f, sl = 0.f, sp = 0.f, sp2 = 0.f;
  for (int r = tid; r < PN; r += 256) {
    float p = pos[r];
    if (p <= thr) { n += 1.f; sl += __logf(p); sp += p; sp2 += p * p; }
  }
  #pragma unroll
  for (int o = 32; o; o >>= 1) {
    n += __shfl_xor(n, o); sl += __shfl_xor(sl, o);
    sp += __shfl_xor(sp, o); sp2 += __shfl_xor(sp2, o);
  }
  if (lane == 0) { red[0][w] = n; red[1][w] = sl; red[2][w] = sp; red[3][w] = sp2; }
  __syncthreads();
  if (tid == 0) {
    acc[3] = red[0][0] + red[0][1] + red[0][2] + red[0][3];
    acc[4] = red[1][0] + red[1][1] + red[1][2] + red[1][3];
    acc[5] = red[2][0] + red[2][1] + red[2][2] + red[2][3];
    acc[6] = red[3][0] + red[3][1] + red[3][2] + red[3][3];
  }
}

__global__ void final_loss_kernel(const float* __restrict__ acc, float* __restrict__ out) {
  double T = acc[0], U = acc[1], V = acc[2];
  double n = acc[3], sl = acc[4], sp = acc[5], sp2 = acc[6];
  double num = n * T - 2.0 * (double)PN * sl + sp * U - 0.5 * sp2 * V;
  out[0] = (float)(num / (2.0 * (double)PN));
}

// ---------------------------------------------------------------- launch
extern "C" void kernel_launch(void* const* d_in, const int* in_sizes, int n_in,
                              void* d_out, int out_size, void* d_ws, size_t ws_size,
                              hipStream_t stream) {
  const float* emb  = (const float*)d_in[0];
  const int2* pairs = (const int2*)d_in[1];
  float* out = (float*)d_out;

  char* w = (char*)d_ws;
  size_t off = 0;
  float*    E     = (float*)(w + off);    off += (size_t)BN * DK * 4;      // 8 MB
  __bf16*   Ebf   = (__bf16*)(w + off);   off += (size_t)BN * DK * 2;      // 4 MB
  float*    S     = (float*)(w + off);    off += (size_t)BN * 4;
  float*    pos   = (float*)(w + off);    off += (size_t)PN * 4;
  float*    thrp  = (float*)(w + off);    off += 256;
  float*    acc   = (float*)(w + off);    off += 256;
  int*      pcnt  = (int*)(w + off);      off += (size_t)BN * 4;
  int*      parts = (int*)(w + off);      off += (size_t)BN * MAXP * 4;    // 512 KB
  int*      rlist = (int*)(w + off);      off += (size_t)BN * 4;
  int*      cnt   = (int*)(w + off);      off += 256;
  _Float16* expc  = (_Float16*)(w + off); off += (size_t)CHUNK * BN * 2;   // 33.5 MB

  prep_clear_kernel<<<BN / 256, 256, 0, stream>>>(pcnt, rlist, cnt, acc);
  normalize_kernel<<<BN / 4, 256, 0, stream>>>(emb, E, Ebf);
  prep_pairs_kernel<<<PN / 256, 256, 0, stream>>>(pairs, pcnt, parts);
  prep_compact_kernel<<<BN / 256, 256, 0, stream>>>(pcnt, rlist, cnt);
  pos_kernel<<<PN / 4, 256, 0, stream>>>(E, pairs, pos);
  pos_thr_kernel<<<1, 256, 0, stream>>>(pos, thrp);
  for (int c = 0; c < NCHUNK; ++c) {
    const int row0 = c * CHUNK;
    gemm_exp_kernel<<<dim3(BN / 128, CHUNK / 128), 256, 0, stream>>>(Ebf, rlist, cnt, expc, row0);
    row_stats_kernel<<<CHUNK, 256, 0, stream>>>(expc, rlist, cnt, pcnt, parts, row0, S);
  }
  pair_terms_kernel<<<1, 256, 0, stream>>>(pairs, S, acc);
  active_sums_kernel<<<1, 256, 0, stream>>>(pos, thrp, acc);
  final_loss_kernel<<<1, 1, 0, stream>>>(acc, out);
}

// Round 4
// 171.719 us; speedup vs baseline: 2.5073x; 1.2197x over previous
//
#include <hip/hip_runtime.h>
#include <stdint.h>

// Problem constants (fixed by the reference)
#define BN    8192    // batch
#define DK    256     // dim
#define PN    4096    // pairs
#define MAXP  16      // max partners tracked per row (Poisson(1); P(>16) ~ 1e-15)
#define HBASE 0x340   // fp16 (bits>>4) base: bins cover values [0.25, ~3.97]
#define RANK_ASC 6553 // ascending rank for the 0.8 quantile boundary (top-1639)

typedef __bf16  bf16_8 __attribute__((ext_vector_type(8)));
typedef __bf16  bf16_4 __attribute__((ext_vector_type(4)));
typedef float   f32x4  __attribute__((ext_vector_type(4)));

__device__ __forceinline__ void gload_lds16(const void* g, void* l) {
  __builtin_amdgcn_global_load_lds(
      (const __attribute__((address_space(1))) unsigned int*)g,
      (__attribute__((address_space(3))) unsigned int*)l, 16, 0, 0);
}

// ---------------------------------------------------------------- prep
__global__ void prep_clear_kernel(int* pcount, int* rowlist, int* cnt, float* acc) {
  const int i = blockIdx.x * 256 + threadIdx.x;
  if (i < BN) { pcount[i] = 0; rowlist[i] = 0; }
  if (i < 8) acc[i] = 0.f;
  if (i == 0) cnt[0] = 0;
}

__global__ void prep_pairs_kernel(const int2* __restrict__ pairs,
                                  int* pcount, int* partners) {
  const int p = blockIdx.x * 256 + threadIdx.x;
  if (p >= PN) return;
  int2 pr = pairs[p];
  int ix = atomicAdd(&pcount[pr.x], 1);
  if (ix < MAXP) partners[pr.x * MAXP + ix] = pr.y;
  int iy = atomicAdd(&pcount[pr.y], 1);
  if (iy < MAXP) partners[pr.y * MAXP + iy] = pr.x;
}

__global__ void prep_compact_kernel(const int* __restrict__ pcount,
                                    int* rowlist, int* cnt) {
  const int i = blockIdx.x * 256 + threadIdx.x;
  if (i < BN && pcount[i] > 0) {
    int pos = atomicAdd(cnt, 1);
    rowlist[pos] = i;
  }
}

// ---------------------------------------------------------------- normalize
__global__ void __launch_bounds__(256) normalize_kernel(
    const float* __restrict__ X, float* __restrict__ E, __bf16* __restrict__ Ebf) {
  const int tid  = threadIdx.x;
  const int lane = tid & 63;
  const int w    = tid >> 6;
  const int row  = blockIdx.x * 4 + w;
  float4 x = ((const float4*)(X + (size_t)row * DK))[lane];
  float ss = x.x * x.x + x.y * x.y + x.z * x.z + x.w * x.w;
  #pragma unroll
  for (int o = 32; o; o >>= 1) ss += __shfl_xor(ss, o);
  float nrm = fmaxf(sqrtf(ss), 1e-8f);
  float4 e;
  e.x = x.x / nrm; e.y = x.y / nrm; e.z = x.z / nrm; e.w = x.w / nrm;
  ((float4*)(E + (size_t)row * DK))[lane] = e;
  bf16_4 b;
  b[0] = (__bf16)e.x; b[1] = (__bf16)e.y; b[2] = (__bf16)e.z; b[3] = (__bf16)e.w;
  *(bf16_4*)(Ebf + (size_t)row * DK + lane * 4) = b;
}

// ---------------------------------------------------------------- pos values
__global__ void __launch_bounds__(256) pos_kernel(
    const float* __restrict__ E, const int2* __restrict__ pairs, float* __restrict__ pos) {
  const int tid  = threadIdx.x;
  const int lane = tid & 63;
  const int w    = tid >> 6;
  const int p    = blockIdx.x * 4 + w;
  int2 pr = pairs[p];
  float4 a = ((const float4*)(E + (size_t)pr.x * DK))[lane];
  float4 b = ((const float4*)(E + (size_t)pr.y * DK))[lane];
  float d = a.x * b.x + a.y * b.y + a.z * b.z + a.w * b.w;
  #pragma unroll
  for (int o = 32; o; o >>= 1) d += __shfl_xor(d, o);
  if (lane == 0) pos[p] = __expf(5.0f * d);
}

// ------------------------------------------------ parallel bin finder (256 bins)
__device__ __forceinline__ void find_bin_256(const unsigned* hist, int rank,
                                             int* sh, unsigned* wtot) {
  const int tid = threadIdx.x, lane = tid & 63, w = tid >> 6;
  unsigned x = hist[tid];
  unsigned pref = x;
  #pragma unroll
  for (int o = 1; o < 64; o <<= 1) {
    unsigned y = __shfl_up(pref, o);
    if (lane >= o) pref += y;
  }
  if (lane == 63) wtot[w] = pref;
  __syncthreads();
  unsigned woff = 0;
  for (int i = 0; i < w; ++i) woff += wtot[i];
  unsigned incl = pref + woff, excl = incl - x;
  if ((unsigned)rank >= excl && (unsigned)rank < incl) { sh[0] = tid; sh[1] = rank - (int)excl; }
  __syncthreads();
}

// ---------------------------------------------------------------- pos quantile
// Single block: exact radix select rank 819 over 4096 positive fp32.
__global__ void __launch_bounds__(256) pos_thr_kernel(
    const float* __restrict__ pos, float* __restrict__ thr_out) {
  __shared__ uint32_t v[PN];
  __shared__ unsigned hist[256];
  __shared__ int sh[2];
  __shared__ unsigned wtot[4];
  const int tid = threadIdx.x;
  for (int i = tid; i < PN; i += 256) v[i] = ((const uint32_t*)pos)[i];
  __syncthreads();
  int rank = 819;                 // 0.2 * 4095 = 819 exactly
  uint32_t prefix = 0;
  for (int pass = 0; pass < 4; ++pass) {
    const int shift = 24 - pass * 8;
    hist[tid] = 0;
    __syncthreads();
    for (int i = tid; i < PN; i += 256) {
      uint32_t x = v[i];
      bool match = (pass == 0) || ((x >> (shift + 8)) == (prefix >> (shift + 8)));
      if (match) atomicAdd(&hist[(x >> shift) & 255u], 1u);
    }
    __syncthreads();
    find_bin_256(hist, rank, sh, wtot);
    prefix |= ((uint32_t)sh[0]) << shift;
    rank = sh[1];
    __syncthreads();
  }
  if (tid == 0) {
    float f;
    __builtin_memcpy(&f, &prefix, 4);
    thr_out[0] = f;
  }
}

// ---------------------------------------------------------------- GEMM + exp
// C[compact_row, col] = exp(5 * E[rowlist[row]] . E[col]); one dispatch over
// all compacted rows. 128x128 tile, BK=32, mfma 16x16x32 bf16,
// global_load_lds(16B) staging (m97 structure).
__global__ void __launch_bounds__(256) gemm_exp_kernel(
    const __bf16* __restrict__ E, const int* __restrict__ rowlist,
    const int* __restrict__ countp, _Float16* __restrict__ out) {
  if ((int)blockIdx.y * 128 >= *countp) return;   // beyond compacted rows
  __shared__ __align__(16) __bf16 sA[128 * 32];
  __shared__ __align__(16) __bf16 sB[128 * 32];
  const int tid  = threadIdx.x;
  const int lane = tid & 63;
  const int w    = tid >> 6;
  const int wm   = w >> 1, wn = w & 1;
  const int trow = blockIdx.y * 128;   // compact-row base
  const int tcol = blockIdx.x * 128;   // global col base
  const int r0   = tid >> 2;           // rows 0..63
  const int seg  = tid & 3;            // 8-bf16 segment of the 32-wide K slice

  const int ga0 = rowlist[trow + r0];
  const int ga1 = rowlist[trow + 64 + r0];
  const __bf16* pa0 = E + (size_t)ga0 * DK + seg * 8;
  const __bf16* pa1 = E + (size_t)ga1 * DK + seg * 8;
  const __bf16* pb0 = E + (size_t)(tcol + r0) * DK + seg * 8;
  const __bf16* pb1 = E + (size_t)(tcol + 64 + r0) * DK + seg * 8;
  __bf16* la0 = &sA[tid * 8];          // r0*32 + seg*8 == tid*8
  __bf16* la1 = &sA[2048 + tid * 8];
  __bf16* lb0 = &sB[tid * 8];
  __bf16* lb1 = &sB[2048 + tid * 8];

  f32x4 acc[4][4];
  #pragma unroll
  for (int i = 0; i < 4; ++i)
    #pragma unroll
    for (int j = 0; j < 4; ++j) {
      f32x4 z = {0.f, 0.f, 0.f, 0.f};
      acc[i][j] = z;
    }

  for (int kt = 0; kt < 8; ++kt) {
    const int k0 = kt * 32;
    __syncthreads();
    gload_lds16(pa0 + k0, la0);
    gload_lds16(pa1 + k0, la1);
    gload_lds16(pb0 + k0, lb0);
    gload_lds16(pb1 + k0, lb1);
    __syncthreads();
    bf16_8 af[4], bfg[4];
    #pragma unroll
    for (int t = 0; t < 4; ++t) {
      af[t]  = *(const bf16_8*)&sA[(wm * 64 + t * 16 + (lane & 15)) * 32 + (lane >> 4) * 8];
      bfg[t] = *(const bf16_8*)&sB[(wn * 64 + t * 16 + (lane & 15)) * 32 + (lane >> 4) * 8];
    }
    #pragma unroll
    for (int i = 0; i < 4; ++i)
      #pragma unroll
      for (int j = 0; j < 4; ++j)
        acc[i][j] = __builtin_amdgcn_mfma_f32_16x16x32_bf16(af[i], bfg[j], acc[i][j], 0, 0, 0);
  }

  const int crow = trow + wm * 64 + (lane >> 4) * 4;  // compact row
  const int ccol = tcol + wn * 64 + (lane & 15);
  #pragma unroll
  for (int i = 0; i < 4; ++i)
    #pragma unroll
    for (int j = 0; j < 4; ++j)
      #pragma unroll
      for (int r = 0; r < 4; ++r) {
        const int row = crow + i * 16 + r;
        const int col = ccol + j * 16;
        out[(size_t)row * BN + col] = (_Float16)__expf(acc[i][j][r] * 5.0f);
      }
}

// ---------------------------------------------------------------- row stats v2
// One block per compacted row; values in registers; one privatized histogram
// pass on spread fp16 bins; S = sum(bin>b) + need * mean(bin b).
__global__ void __launch_bounds__(256) row_stats_kernel(
    const _Float16* __restrict__ expmat, const int* __restrict__ rowlist,
    const int* __restrict__ countp, const int* __restrict__ pcount,
    const int* __restrict__ partners, float* __restrict__ S) {
  __shared__ unsigned hist[4][256];
  __shared__ unsigned total[256];
  __shared__ int plist[MAXP + 1];
  __shared__ int sh[2];
  __shared__ unsigned wtot[4];
  __shared__ float redf[2][4];
  __shared__ unsigned redc[4];
  const int rloc = blockIdx.x;
  if (rloc >= *countp) return;            // uniform early exit (unused rows)
  const int grow = rowlist[rloc];
  const int tid = threadIdx.x, lane = tid & 63, w = tid >> 6;

  uint4 rv[4];
  const uint4* src = (const uint4*)(expmat + (size_t)rloc * BN);
  #pragma unroll
  for (int q = 0; q < 4; ++q) rv[q] = src[q * 256 + tid];

  int np = pcount[grow]; if (np > MAXP) np = MAXP;
  if (tid < np) plist[tid] = partners[grow * MAXP + tid];
  if (tid == np) plist[tid] = grow;       // diagonal
  ((unsigned*)hist)[tid]       = 0;
  ((unsigned*)hist)[tid + 256] = 0;
  ((unsigned*)hist)[tid + 512] = 0;
  ((unsigned*)hist)[tid + 768] = 0;
  __syncthreads();

  unsigned short hv[32];
  #pragma unroll
  for (int q = 0; q < 4; ++q) {
    union { uint4 u; unsigned short s[8]; } cv;
    cv.u = rv[q];
    #pragma unroll
    for (int j = 0; j < 8; ++j) hv[q * 8 + j] = cv.s[j];
  }

  for (int e = 0; e <= np; ++e) {
    int c = plist[e];
    if (((c >> 3) & 255) == tid) hv[((c >> 11) << 3) | (c & 7)] = 0;
  }

  unsigned* h = hist[w];
  #pragma unroll
  for (int e = 0; e < 32; ++e) {
    int bb = (int)(hv[e] >> 4) - HBASE;
    bb = bb < 0 ? 0 : (bb > 255 ? 255 : bb);
    atomicAdd(&h[bb], 1u);
  }
  __syncthreads();
  total[tid] = hist[0][tid] + hist[1][tid] + hist[2][tid] + hist[3][tid];
  __syncthreads();
  find_bin_256(total, RANK_ASC, sh, wtot);
  const int b    = sh[0];
  const int need = (int)total[b] - sh[1];

  float shi = 0.f, sin_ = 0.f; unsigned cin = 0;
  #pragma unroll
  for (int e = 0; e < 32; ++e) {
    unsigned short x = hv[e];
    int bb = (int)(x >> 4) - HBASE;
    bb = bb < 0 ? 0 : (bb > 255 ? 255 : bb);
    _Float16 hf; __builtin_memcpy(&hf, &x, 2);
    float v = (float)hf;
    if (bb > b) shi += v;
    else if (bb == b) { sin_ += v; cin++; }
  }
  #pragma unroll
  for (int o = 32; o; o >>= 1) {
    shi  += __shfl_xor(shi, o);
    sin_ += __shfl_xor(sin_, o);
    cin  += __shfl_xor(cin, o);
  }
  if (lane == 0) { redf[0][w] = shi; redf[1][w] = sin_; redc[w] = cin; }
  __syncthreads();
  if (tid == 0) {
    float SHI = redf[0][0] + redf[0][1] + redf[0][2] + redf[0][3];
    float SIN = redf[1][0] + redf[1][1] + redf[1][2] + redf[1][3];
    float CIN = (float)(redc[0] + redc[1] + redc[2] + redc[3]);
    S[grow] = SHI + (float)need * (SIN / CIN);
  }
}

// ---------------------------------------------------------------- loss (factorized)
// log1p(S/p) = logS - logp + p/S - p^2/(2S^2) + O((p/S)^3), p/S <= ~3e-4.
// acc layout: [0]=T [1]=U [2]=V [3]=n [4]=sl [5]=sp [6]=sp2
__global__ void __launch_bounds__(256) pair_terms_kernel(
    const int2* __restrict__ pairs, const float* __restrict__ S,
    float* __restrict__ acc) {
  __shared__ float red[3][4];
  const int tid = threadIdx.x, lane = tid & 63, w = tid >> 6;
  float t = 0.f, u = 0.f, v = 0.f;
  for (int c = tid; c < PN; c += 256) {
    int2 pr = pairs[c];
    float s1 = S[pr.x], s2 = S[pr.y];
    float i1 = 1.f / s1, i2 = 1.f / s2;
    t += __logf(s1) + __logf(s2);
    u += i1 + i2;
    v += i1 * i1 + i2 * i2;
  }
  #pragma unroll
  for (int o = 32; o; o >>= 1) {
    t += __shfl_xor(t, o); u += __shfl_xor(u, o); v += __shfl_xor(v, o);
  }
  if (lane == 0) { red[0][w] = t; red[1][w] = u; red[2][w] = v; }
  __syncthreads();
  if (tid == 0) {
    acc[0] = red[0][0] + red[0][1] + red[0][2] + red[0][3];
    acc[1] = red[1][0] + red[1][1] + red[1][2] + red[1][3];
    acc[2] = red[2][0] + red[2][1] + red[2][2] + red[2][3];
  }
}

__global__ void __launch_bounds__(256) active_sums_kernel(
    const float* __restrict__ pos, const float* __restrict__ thr_p,
    float* __restrict__ acc) {
  __shared__ float red[4][4];
  const int tid = threadIdx.x, lane = tid & 63, w = tid >> 6;
  const float thr = thr_p[0];
  float n = 0.f, sl = 0.f, sp = 0.f, sp2 = 0.f;
  for (int r = tid; r < PN; r += 256) {
    float p = pos[r];
    if (p <= thr) { n += 1.f; sl += __logf(p); sp += p; sp2 += p * p; }
  }
  #pragma unroll
  for (int o = 32; o; o >>= 1) {
    n += __shfl_xor(n, o); sl += __shfl_xor(sl, o);
    sp += __shfl_xor(sp, o); sp2 += __shfl_xor(sp2, o);
  }
  if (lane == 0) { red[0][w] = n; red[1][w] = sl; red[2][w] = sp; red[3][w] = sp2; }
  __syncthreads();
  if (tid == 0) {
    acc[3] = red[0][0] + red[0][1] + red[0][2] + red[0][3];
    acc[4] = red[1][0] + red[1][1] + red[1][2] + red[1][3];
    acc[5] = red[2][0] + red[2][1] + red[2][2] + red[2][3];
    acc[6] = red[3][0] + red[3][1] + red[3][2] + red[3][3];
  }
}

__global__ void final_loss_kernel(const float* __restrict__ acc, float* __restrict__ out) {
  double T = acc[0], U = acc[1], V = acc[2];
  double n = acc[3], sl = acc[4], sp = acc[5], sp2 = acc[6];
  double num = n * T - 2.0 * (double)PN * sl + sp * U - 0.5 * sp2 * V;
  out[0] = (float)(num / (2.0 * (double)PN));
}

// ---------------------------------------------------------------- launch
extern "C" void kernel_launch(void* const* d_in, const int* in_sizes, int n_in,
                              void* d_out, int out_size, void* d_ws, size_t ws_size,
                              hipStream_t stream) {
  const float* emb  = (const float*)d_in[0];
  const int2* pairs = (const int2*)d_in[1];
  float* out = (float*)d_out;

  char* w = (char*)d_ws;
  size_t off = 0;
  float*    E     = (float*)(w + off);    off += (size_t)BN * DK * 4;      // 8 MB
  __bf16*   Ebf   = (__bf16*)(w + off);   off += (size_t)BN * DK * 2;      // 4 MB
  float*    S     = (float*)(w + off);    off += (size_t)BN * 4;
  float*    pos   = (float*)(w + off);    off += (size_t)PN * 4;
  float*    thrp  = (float*)(w + off);    off += 256;
  float*    acc   = (float*)(w + off);    off += 256;
  int*      pcnt  = (int*)(w + off);      off += (size_t)BN * 4;
  int*      parts = (int*)(w + off);      off += (size_t)BN * MAXP * 4;    // 512 KB
  int*      rlist = (int*)(w + off);      off += (size_t)BN * 4;
  int*      cnt   = (int*)(w + off);      off += 256;
  _Float16* expc  = (_Float16*)(w + off); off += (size_t)BN * BN * 2;      // 134 MB worst case

  prep_clear_kernel<<<BN / 256, 256, 0, stream>>>(pcnt, rlist, cnt, acc);
  normalize_kernel<<<BN / 4, 256, 0, stream>>>(emb, E, Ebf);
  prep_pairs_kernel<<<PN / 256, 256, 0, stream>>>(pairs, pcnt, parts);
  prep_compact_kernel<<<BN / 256, 256, 0, stream>>>(pcnt, rlist, cnt);
  pos_kernel<<<PN / 4, 256, 0, stream>>>(E, pairs, pos);
  pos_thr_kernel<<<1, 256, 0, stream>>>(pos, thrp);
  gemm_exp_kernel<<<dim3(BN / 128, BN / 128), 256, 0, stream>>>(Ebf, rlist, cnt, expc);
  row_stats_kernel<<<BN, 256, 0, stream>>>(expc, rlist, cnt, pcnt, parts, S);
  pair_terms_kernel<<<1, 256, 0, stream>>>(pairs, S, acc);
  active_sums_kernel<<<1, 256, 0, stream>>>(pos, thrp, acc);
  final_loss_kernel<<<1, 1, 0, stream>>>(acc, out);
}